// Round 8
// baseline (267.869 us; speedup 1.0000x reference)
//
#include <hip/hip_runtime.h>
#include <hip/hip_bf16.h>

// ---------- types / helpers ----------
typedef __attribute__((ext_vector_type(4))) float f32x4;      // MFMA C/D frag

__device__ __forceinline__ unsigned short f2bf(float f) {  // round-to-nearest-even
    union { float f; unsigned int u; } v; v.f = f;
    unsigned int u = v.u;
    unsigned int r = (u + 0x7FFFu + ((u >> 16) & 1u)) >> 16;
    return (unsigned short)r;
}
// float -> OCP e4m3fn byte (RNE on normals, RN on subnormals, saturate to 448)
__device__ __forceinline__ unsigned char f2fp8(float f) {
    unsigned char s = (__float_as_uint(f) >> 24) & 0x80;
    float a = fabsf(f);
    if (a >= 448.f) return s | 0x7E;
    if (a < 0.015625f) {                       // subnormal: step 2^-9; q=8 -> min normal
        int q = (int)(a * 512.0f + 0.5f);
        return s | (unsigned char)q;
    }
    unsigned int u = __float_as_uint(a);
    u += 0x0007FFFF + ((u >> 20) & 1);         // RNE to 3 mantissa bits (carry-safe)
    int e8 = (int)((u >> 23) & 0xFF) - 120;    // -127+7
    if (e8 >= 16) return s | 0x7E;
    return s | (unsigned char)((e8 << 3) | ((u >> 20) & 7));
}
__device__ __forceinline__ void gload_lds16(const void* g, void* l) {
    // async global->LDS, 16B/lane; LDS dest = wave-uniform base + lane*16
    __builtin_amdgcn_global_load_lds((const __attribute__((address_space(1))) void*)g,
                                     (__attribute__((address_space(3))) void*)l, 16, 0, 0);
}

// ---------- constants ----------
#define BATCH 256
#define CHAN  768
#define HW    196
#define SPS   196
#define HID   512
#define MROWS 50176   // BATCH*SPS
#define K1    1536    // 2*CHAN
#define WSCL  64.0f           // weights pre-scaled by 64 (e4m3 subnormal dodge)
#define WINV  0.015625f       // 1/64 applied in epilogue

// fp8 8-phase GEMM geometry: BM=BN=256, BK=64 elems (=64B rows); 8 waves (2M x 4N),
// per-wave 128x64 output (acc[8][4]).  LDS: A and B each TRIPLE-buffered (slot t%3),
// 16KB per tile (2 halves of 128 rows x 64B) -> 6 x 16KB = 96KB, 1 block/CU.
#define HHALF 8192
#define ASLOT 16384
#define BOFF  49152   // 3 * ASLOT

// ---------- weight prep: in [K][N] fp32 -> out [N][K] fp8 of (w * 64) ----------
__global__ void transpose_cast_fp8(const float* __restrict__ in, unsigned char* __restrict__ out,
                                   int K, int N) {
    int idx = blockIdx.x * 256 + threadIdx.x;
    if (idx >= K * N) return;
    int n = idx / K, k = idx - n * K;
    out[idx] = f2fp8(in[(size_t)k * N + n] * WSCL);
}

// ---------- gather + out-init: feats fp8; out[0:2M)=b3 (pred init); out[2M:4M)=deltaxy ----------
__global__ __launch_bounds__(256) void gather_feats(const float* __restrict__ x,
                                                    const int* __restrict__ pxs,
                                                    const int* __restrict__ pys,
                                                    const float* __restrict__ b3,
                                                    unsigned char* __restrict__ feats,
                                                    float* __restrict__ out) {
    __shared__ float lds[64 * 197];   // pitch 197: stride-5 banks, conflict-free
    int chunk = blockIdx.x;           // 0..11 (64-channel chunk)
    int b     = blockIdx.y;           // 0..255
    int c0 = chunk * 64;
    const float* xb = x + ((size_t)b * CHAN + c0) * HW;
    for (int t = threadIdx.x; t < 64 * HW; t += 256) {
        int j = t / HW, p = t - j * HW;
        lds[j * 197 + p] = xb[t];     // coalesced read of 64 full channels
    }
    if (chunk == 0) {                 // per-batch: init pred rows to b3, write deltaxy
        float b30 = b3[0], b31 = b3[1];
        for (int i = threadIdx.x; i < SPS * 2; i += 256) {
            int idx = b * SPS * 2 + i;
            out[idx] = (i & 1) ? b31 : b30;                          // pred init (atomics add on top)
            out[MROWS * 2 + idx] = (float)(pxs[idx] - pys[idx]) + 13.0f;  // (H-1)=13
        }
    }
    __syncthreads();
    int w = threadIdx.x >> 6, lane = threadIdx.x & 63;
    for (int s = w; s < SPS; s += 4) {
        int base = (b * SPS + s) * 2;
        int ix = pxs[base] * 14 + pxs[base + 1];
        int iy = pys[base] * 14 + pys[base + 1];
        size_t ro = (size_t)(b * SPS + s) * K1;
        feats[ro + c0 + lane]        = f2fp8(lds[lane * 197 + ix]);
        feats[ro + CHAN + c0 + lane] = f2fp8(lds[lane * 197 + iy]);
    }
}

// ---------- 256x256 fp8 MFMA GEMM, 8-phase + counted vmcnt (T3+T4), swizzle, T5 ----------
// C = relu((A @ Bt^T)/64 + bias); A[M][K] fp8, Bt[N=512][K] fp8 (weights pre-scaled x64).
// Grid 1-D: bid -> (mTile = bid>>1, nTile = bid&1).
// Schedule per K-tile t (4 phases, 2 barriers each); A,B triple-buffered slot t%3:
//   ph1: ds(B kk0, A mh0 kk0) | stage B(t+2)h0 | bar | 16-MFMA | bar
//   ph2: ds(A mh1 kk0)        | stage B(t+2)h1 | bar | 16-MFMA | bar
//   ph3: ds(B kk1, A mh0 kk1) | stage A(t+2)h0 | bar | 16-MFMA | bar
//   ph4: ds(A mh1 kk1)        | stage A(t+2)h1 | bar | 16-MFMA | vmcnt(4) | bar
// Ledger (1 gload/thread per half; in-order retire): queue at ph4(t) =
// [B(t+1)h0,h1 (ph1/2 of t-1), A(t+1)h0,h1 (ph3/4 of t-1), B(t+2)h0,h1, A(t+2)h0,h1];
// vmcnt(4) retires A(t+1)+B(t+1) (read from ph1(t+1)) and leaves t+2's 4 in flight
// (>= 1 full tile-time of HBM cover).  Never vmcnt(0) mid-loop.
// Tail: clamped data tile staged into slot (tt+2)%3 which no remaining tile reads;
// vmcnt(0) after loop.  LDS swizzle (b64 reads): chunk c' = c ^ ((row>>1)&3), 2-way=free;
// stage applies the same XOR on the SOURCE chunk (involution).
// predMode: accumulate pred = relu(h2)@W3 into out via atomics instead of storing C.
__global__ __launch_bounds__(512, 2) void gemm8p_fp8(const unsigned char* __restrict__ A,
                                                     const unsigned char* __restrict__ Bt,
                                                     const float* __restrict__ bias,
                                                     unsigned char* __restrict__ C,
                                                     const float* __restrict__ W3,
                                                     float* __restrict__ out,
                                                     int Kd, int predMode) {
    extern __shared__ char smem[];    // 98304 B
    const int t = threadIdx.x;
    const int wid = t >> 6, lane = t & 63;
    const int wr = wid >> 2, wcn = wid & 3;      // 2M x 4N waves; wave owns 128 rows x 64 cols
    const int lr = lane & 15, lk = lane >> 4;
    const int mBase = (blockIdx.x >> 1) * 256;
    const int nBase = (blockIdx.x & 1) * 256;
    const int nK = Kd >> 6;
    f32x4 acc[8][4] = {};

    // stage half h of a K-tile (data tile td, dest slot ts%3); 1 gload/thread = 8KB
    auto stageA = [&](int ts, int td, int h) {
        char* dst = smem + (ts % 3) * ASLOT + h * HHALF;
        int row = t >> 2;                        // half-local row 0..127
        int cs  = (t & 3) ^ ((row >> 1) & 3);    // inverse-swizzled source 16B chunk
        gload_lds16((const char*)A + ((size_t)(mBase + h * 128 + row) * Kd + (td << 6) + cs * 16),
                    dst + t * 16);
    };
    auto stageB = [&](int ts, int td, int h) {
        char* dst = smem + BOFF + (ts % 3) * ASLOT + h * HHALF;
        int row = t >> 2;
        int cs  = (t & 3) ^ ((row >> 1) & 3);
        gload_lds16((const char*)Bt + ((size_t)(nBase + h * 128 + row) * Kd + (td << 6) + cs * 16),
                    dst + t * 16);
    };
    auto readA = [&](int tt, int mi, int kk) -> long long {   // 8B fp8 frag
        int ra = wr * 128 + mi * 16 + lr;        // 0..255
        int r  = ra & 127;
        int c  = (kk * 2 + (lk >> 1)) ^ ((r >> 1) & 3);
        return *(const long long*)(smem + (tt % 3) * ASLOT + (ra >> 7) * HHALF
                                   + r * 64 + c * 16 + (lk & 1) * 8);
    };
    auto readB = [&](int tt, int n, int kk) -> long long {
        int rb = wcn * 64 + n * 16 + lr;         // 0..255
        int r  = rb & 127;
        int c  = (kk * 2 + (lk >> 1)) ^ ((r >> 1) & 3);
        return *(const long long*)(smem + BOFF + (tt % 3) * ASLOT + (rb >> 7) * HHALF
                                   + r * 64 + c * 16 + (lk & 1) * 8);
    };
    auto doQuad = [&](int mh, long long (&af)[4], long long (&bf)[4]) {   // 16-MFMA cluster (T5)
        __builtin_amdgcn_s_setprio(1);
        #pragma unroll
        for (int m = 0; m < 4; ++m)
            #pragma unroll
            for (int n = 0; n < 4; ++n)
                acc[mh * 4 + m][n] = __builtin_amdgcn_mfma_f32_16x16x32_fp8_fp8(
                    af[m], bf[n], acc[mh * 4 + m][n], 0, 0, 0);
        __builtin_amdgcn_s_setprio(0);
    };

    // prologue: tiles 0,1 (A+B) staged + fully drained
    stageA(0, 0, 0); stageA(0, 0, 1); stageA(1, 1, 0); stageA(1, 1, 1);
    stageB(0, 0, 0); stageB(0, 0, 1); stageB(1, 1, 0); stageB(1, 1, 1);
    asm volatile("s_waitcnt vmcnt(0)" ::: "memory");
    __builtin_amdgcn_s_barrier();

    for (int tt = 0; tt < nK; ++tt) {
        int tS = (tt + 2 < nK) ? tt + 2 : nK - 1;   // clamped data tile (dest slot unread when clamped)
        long long af[4], bfr[4];
        // ---- ph1: kk0, mh0 ----
        #pragma unroll
        for (int n = 0; n < 4; ++n) bfr[n] = readB(tt, n, 0);
        #pragma unroll
        for (int m = 0; m < 4; ++m) af[m] = readA(tt, m, 0);
        stageB(tt + 2, tS, 0);
        __builtin_amdgcn_s_barrier();
        doQuad(0, af, bfr);
        __builtin_amdgcn_s_barrier();
        // ---- ph2: kk0, mh1 ---- (B frags reused)
        #pragma unroll
        for (int m = 0; m < 4; ++m) af[m] = readA(tt, m + 4, 0);
        stageB(tt + 2, tS, 1);
        __builtin_amdgcn_s_barrier();
        doQuad(1, af, bfr);
        __builtin_amdgcn_s_barrier();
        // ---- ph3: kk1, mh0 ----
        #pragma unroll
        for (int n = 0; n < 4; ++n) bfr[n] = readB(tt, n, 1);
        #pragma unroll
        for (int m = 0; m < 4; ++m) af[m] = readA(tt, m, 1);
        stageA(tt + 2, tS, 0);
        __builtin_amdgcn_s_barrier();
        doQuad(0, af, bfr);
        __builtin_amdgcn_s_barrier();
        // ---- ph4: kk1, mh1 ----
        #pragma unroll
        for (int m = 0; m < 4; ++m) af[m] = readA(tt, m + 4, 1);
        stageA(tt + 2, tS, 1);
        __builtin_amdgcn_s_barrier();
        doQuad(1, af, bfr);
        asm volatile("s_waitcnt vmcnt(4)" ::: "memory");   // t+1 (A,B) resident; t+2 flies
        __builtin_amdgcn_s_barrier();
    }
    asm volatile("s_waitcnt vmcnt(0)" ::: "memory");       // drain tail clamp-stages before exit

    if (!predMode) {
        // epilogue: h1 = relu(acc/64 + b1) -> fp8.  C row=(lane>>4)*4+j, col=lane&15
        #pragma unroll
        for (int n = 0; n < 4; ++n) {
            int c = nBase + wcn * 64 + n * 16 + lr;
            float bv = bias[c];
            #pragma unroll
            for (int m = 0; m < 8; ++m) {
                int r0 = mBase + wr * 128 + m * 16 + lk * 4;
                #pragma unroll
                for (int j = 0; j < 4; ++j)
                    C[(size_t)(r0 + j) * HID + c] = f2fp8(fmaxf(acc[m][n][j] * WINV + bv, 0.f));
            }
        }
    } else {
        // fused final layer: pred[r][o] += sum_c relu(acc/64 + b2)[r][c] * W3[c][o]
        float w3v[4][2], bv[4];
        #pragma unroll
        for (int n = 0; n < 4; ++n) {
            int c = nBase + wcn * 64 + n * 16 + lr;
            w3v[n][0] = W3[c * 2 + 0];
            w3v[n][1] = W3[c * 2 + 1];
            bv[n] = bias[c];
        }
        #pragma unroll
        for (int m = 0; m < 8; ++m) {
            #pragma unroll
            for (int j = 0; j < 4; ++j) {
                float p0 = 0.f, p1 = 0.f;
                #pragma unroll
                for (int n = 0; n < 4; ++n) {
                    float v = fmaxf(acc[m][n][j] * WINV + bv[n], 0.f);
                    p0 += v * w3v[n][0];
                    p1 += v * w3v[n][1];
                }
                #pragma unroll
                for (int msk = 1; msk < 16; msk <<= 1) {   // reduce over the 16 lr-lanes (same row)
                    p0 += __shfl_xor(p0, msk);
                    p1 += __shfl_xor(p1, msk);
                }
                if (lr == 0) {
                    int r = mBase + wr * 128 + m * 16 + lk * 4 + j;
                    atomicAdd(&out[r * 2 + 0], p0);   // 8 wave-partials per row (2 nTiles x 4 wcn)
                    atomicAdd(&out[r * 2 + 1], p1);
                }
            }
        }
    }
}

// ---------- launch ----------
extern "C" void kernel_launch(void* const* d_in, const int* in_sizes, int n_in,
                              void* d_out, int out_size, void* d_ws, size_t ws_size,
                              hipStream_t stream) {
    const float* x  = (const float*)d_in[0];
    const float* W1 = (const float*)d_in[1];
    const float* b1 = (const float*)d_in[2];
    const float* W2 = (const float*)d_in[3];
    const float* b2 = (const float*)d_in[4];
    const float* W3 = (const float*)d_in[5];
    const float* b3 = (const float*)d_in[6];
    const int*  pxs = (const int*)d_in[7];
    const int*  pys = (const int*)d_in[8];
    float* out = (float*)d_out;
    char* ws = (char*)d_ws;

    // ws layout (bytes), fp8: W1t 786,432 | W2t 262,144 | h1 25,690,112 | feats 77,070,336
    unsigned char* W1t   = (unsigned char*)(ws + 0);
    unsigned char* W2t   = (unsigned char*)(ws + 786432);
    unsigned char* h1    = (unsigned char*)(ws + 1048576);
    unsigned char* feats = (unsigned char*)(ws + 26738688);   // end 103,809,024

    hipFuncSetAttribute((const void*)gemm8p_fp8,
                        hipFuncAttributeMaxDynamicSharedMemorySize, 98304);

    transpose_cast_fp8<<<(K1 * HID + 255) / 256, 256, 0, stream>>>(W1, W1t, K1, HID);
    transpose_cast_fp8<<<(HID * HID + 255) / 256, 256, 0, stream>>>(W2, W2t, HID, HID);
    // gather also initializes out: pred rows = b3 (GEMM2 atomics accumulate), deltaxy written
    gather_feats<<<dim3(12, BATCH), 256, 0, stream>>>(x, pxs, pys, b3, feats, out);
    // GEMM1: h1 = relu(feats @ (64*W1t)^T /64 + b1)   grid = 196 mTiles * 2 nTiles = 392
    gemm8p_fp8<<<(MROWS / 256) * 2, 512, 98304, stream>>>(
        feats, W1t, b1, h1, nullptr, nullptr, K1, 0);
    // GEMM2 (+fused GEMM3): out[0:2M) += relu(h1 @ (64*W2t)^T /64 + b2) @ W3
    gemm8p_fp8<<<(MROWS / 256) * 2, 512, 98304, stream>>>(
        h1, W2t, b2, nullptr, W3, out, HID, 1);
}

// Round 9
// 224.538 us; speedup vs baseline: 1.1930x; 1.1930x over previous
//
#include <hip/hip_runtime.h>
#include <hip/hip_bf16.h>

// ---------- types / helpers ----------
typedef __attribute__((ext_vector_type(4))) float f32x4;   // MFMA C/D frag
typedef __attribute__((ext_vector_type(4))) int   int4v;   // one ds_read_b128
typedef __attribute__((ext_vector_type(8))) int   int8v;   // K=128 fp8 A/B frag (32B)

// float -> OCP e4m3fn byte (RNE on normals, RN on subnormals, saturate to 448)
__device__ __forceinline__ unsigned char f2fp8(float f) {
    unsigned char s = (__float_as_uint(f) >> 24) & 0x80;
    float a = fabsf(f);
    if (a >= 448.f) return s | 0x7E;
    if (a < 0.015625f) {                       // subnormal: step 2^-9
        int q = (int)(a * 512.0f + 0.5f);
        return s | (unsigned char)q;
    }
    unsigned int u = __float_as_uint(a);
    u += 0x0007FFFF + ((u >> 20) & 1);         // RNE to 3 mantissa bits (carry-safe)
    int e8 = (int)((u >> 23) & 0xFF) - 120;    // -127+7
    if (e8 >= 16) return s | 0x7E;
    return s | (unsigned char)((e8 << 3) | ((u >> 20) & 7));
}
__device__ __forceinline__ void gload_lds16(const void* g, void* l) {
    // async global->LDS, 16B/lane; LDS dest = wave-uniform base + lane*16
    __builtin_amdgcn_global_load_lds((const __attribute__((address_space(1))) void*)g,
                                     (__attribute__((address_space(3))) void*)l, 16, 0, 0);
}

// ---------- constants ----------
#define BATCH 256
#define CHAN  768
#define HW    196
#define SPS   196
#define HID   512
#define MROWS 50176   // BATCH*SPS
#define K1    1536    // 2*CHAN
#define WSCL  64.0f           // weights pre-scaled by 64 (e4m3 subnormal dodge)
#define WINV  0.015625f       // 1/64 applied in epilogue
#define SC1   0x7F7F7F7F      // E8M0 scale 1.0 in every byte (mapping-invariant)

// MX-fp8 K=128 GEMM: BM=BN=256, BK=128 (128B LDS rows); 8 waves (2M x 4N),
// per-wave 128x64 (acc[8][4]).  LDS 160KB exactly: A double (2x32KB, slot t&1),
// B triple (3x32KB at +64KB, slot t%3).  b128 reads, chunk ^= (row&7): the
// R7-measured conflict-free pattern (each 8-lane phase-group spans all 32 banks).
#define ATILE 32768
#define HHALF 16384
#define BOFF  65536

// ---------- weight prep: in [K][N] fp32 -> out [N][K] fp8 of (w * 64) ----------
__global__ void transpose_cast_fp8(const float* __restrict__ in, unsigned char* __restrict__ out,
                                   int K, int N) {
    int idx = blockIdx.x * 256 + threadIdx.x;
    if (idx >= K * N) return;
    int n = idx / K, k = idx - n * K;
    out[idx] = f2fp8(in[(size_t)k * N + n] * WSCL);
}

// ---------- gather + out-init: feats fp8; out[0:2M)=b3 (pred init); out[2M:4M)=deltaxy ----------
__global__ __launch_bounds__(256) void gather_feats(const float* __restrict__ x,
                                                    const int* __restrict__ pxs,
                                                    const int* __restrict__ pys,
                                                    const float* __restrict__ b3,
                                                    unsigned char* __restrict__ feats,
                                                    float* __restrict__ out) {
    __shared__ float lds[64 * 197];   // pitch 197: stride-5 banks, conflict-free
    int chunk = blockIdx.x;           // 0..11 (64-channel chunk)
    int b     = blockIdx.y;           // 0..255
    int c0 = chunk * 64;
    const float* xb = x + ((size_t)b * CHAN + c0) * HW;
    for (int t = threadIdx.x; t < 64 * HW; t += 256) {
        int j = t / HW, p = t - j * HW;
        lds[j * 197 + p] = xb[t];     // coalesced read of 64 full channels
    }
    if (chunk == 0) {                 // per-batch: init pred rows to b3, write deltaxy
        float b30 = b3[0], b31 = b3[1];
        for (int i = threadIdx.x; i < SPS * 2; i += 256) {
            int idx = b * SPS * 2 + i;
            out[idx] = (i & 1) ? b31 : b30;                          // pred init (atomics add on top)
            out[MROWS * 2 + idx] = (float)(pxs[idx] - pys[idx]) + 13.0f;  // (H-1)=13
        }
    }
    __syncthreads();
    int w = threadIdx.x >> 6, lane = threadIdx.x & 63;
    for (int s = w; s < SPS; s += 4) {
        int base = (b * SPS + s) * 2;
        int ix = pxs[base] * 14 + pxs[base + 1];
        int iy = pys[base] * 14 + pys[base + 1];
        size_t ro = (size_t)(b * SPS + s) * K1;
        feats[ro + c0 + lane]        = f2fp8(lds[lane * 197 + ix]);
        feats[ro + CHAN + c0 + lane] = f2fp8(lds[lane * 197 + iy]);
    }
}

// ---------- 256x256 MX-fp8 K=128 MFMA GEMM, 2-phase/tile + counted vmcnt, T2, T5 ----------
// C = relu((A @ Bt^T)/64 + bias); A[M][K] fp8, Bt[N=512][K] fp8 (weights pre-scaled x64).
// Grid 1-D: bid -> (mTile = bid>>1, nTile = bid&1).
// Per K-tile t (A slot t&1, B slot t%3), 2 phases:
//   ph1: ds(B all-n, A mi0-3: 16 b128) | stage A(t+1) [4 gload] | bar | 16 MFMA | bar
//   ph2: ds(A mi4-7: 8 b128)           | stage B(t+2) [4 gload] | bar | 16 MFMA | vmcnt(4) | bar
// Ledger (in-order retire; 4 loads/stage): prologue A0,B0,B1 (12) then vmcnt(4).
// At ph2(t) end: outstanding = B(t+1)[4] + A(t+1)[4] + B(t+2)[4] = 12; vmcnt(4)
// retires B(t+1)+A(t+1) (read at ph1(t+1)); B(t+2) stays in flight (2-tile cover).
// Tail: clamped data tile -> dest slots provably unread (A: (t+1)&1 != t&1;
// B: (t+2)%3 != remaining-read slots); vmcnt(0) after loop.
// predMode: pred = relu(h2)@W3 reduced via LDS, 512 atomics/block (not 32k).
__global__ __launch_bounds__(512, 2) void gemm_mx(const unsigned char* __restrict__ A,
                                                  const unsigned char* __restrict__ Bt,
                                                  const float* __restrict__ bias,
                                                  unsigned char* __restrict__ C,
                                                  const float* __restrict__ W3,
                                                  float* __restrict__ out,
                                                  int Kd, int predMode) {
    extern __shared__ char smem[];    // 163840 B
    const int t = threadIdx.x;
    const int wid = t >> 6, lane = t & 63;
    const int wr = wid >> 2, wcn = wid & 3;      // 2M x 4N waves; wave owns 128 rows x 64 cols
    const int lr = lane & 15, lk = lane >> 4;
    const int mBase = (blockIdx.x >> 1) * 256;
    const int nBase = (blockIdx.x & 1) * 256;
    const int nK = Kd >> 7;                      // BK=128
    f32x4 acc[8][4] = {};

    // stage one 32KB K-tile (256 rows x 128B); 4 gload16/thread; inverse-swizzled source
    auto stageA = [&](int ts, int td) {
        char* dst = smem + (ts & 1) * ATILE;
        #pragma unroll
        for (int i = 0; i < 4; ++i) {
            int lin = i * 512 + t;
            int row = lin >> 3;                  // 0..255
            int cs  = (lin & 7) ^ (row & 7);
            gload_lds16((const char*)A + ((size_t)(mBase + row) * Kd + (td << 7) + cs * 16),
                        dst + lin * 16);
        }
    };
    auto stageB = [&](int ts, int td) {
        char* dst = smem + BOFF + (ts % 3) * ATILE;
        #pragma unroll
        for (int i = 0; i < 4; ++i) {
            int lin = i * 512 + t;
            int row = lin >> 3;
            int cs  = (lin & 7) ^ (row & 7);
            gload_lds16((const char*)Bt + ((size_t)(nBase + row) * Kd + (td << 7) + cs * 16),
                        dst + lin * 16);
        }
    };
    auto readA = [&](int tt, int mi) -> int8v {   // 32B frag = 2 swizzled b128
        int ra = wr * 128 + mi * 16 + lr;         // 0..255
        int r  = ra & 127;
        const char* p = smem + (tt & 1) * ATILE + (ra >> 7) * HHALF + r * 128;
        int4v lo = *(const int4v*)(p + (((2 * lk + 0) ^ (r & 7)) * 16));
        int4v hi = *(const int4v*)(p + (((2 * lk + 1) ^ (r & 7)) * 16));
        int8v a;
        a[0] = lo[0]; a[1] = lo[1]; a[2] = lo[2]; a[3] = lo[3];
        a[4] = hi[0]; a[5] = hi[1]; a[6] = hi[2]; a[7] = hi[3];
        return a;
    };
    auto readB = [&](int tt, int n) -> int8v {
        int rb = wcn * 64 + n * 16 + lr;          // 0..255
        int r  = rb & 127;
        const char* p = smem + BOFF + (tt % 3) * ATILE + (rb >> 7) * HHALF + r * 128;
        int4v lo = *(const int4v*)(p + (((2 * lk + 0) ^ (r & 7)) * 16));
        int4v hi = *(const int4v*)(p + (((2 * lk + 1) ^ (r & 7)) * 16));
        int8v b;
        b[0] = lo[0]; b[1] = lo[1]; b[2] = lo[2]; b[3] = lo[3];
        b[4] = hi[0]; b[5] = hi[1]; b[6] = hi[2]; b[7] = hi[3];
        return b;
    };
    auto doQuad = [&](int mh, int8v (&af)[4], int8v (&bf)[4]) {   // 16-MFMA cluster (T5)
        __builtin_amdgcn_s_setprio(1);
        #pragma unroll
        for (int m = 0; m < 4; ++m)
            #pragma unroll
            for (int n = 0; n < 4; ++n)
                acc[mh * 4 + m][n] = __builtin_amdgcn_mfma_scale_f32_16x16x128_f8f6f4(
                    af[m], bf[n], acc[mh * 4 + m][n], 0, 0, 0, SC1, 0, SC1);
        __builtin_amdgcn_s_setprio(0);
    };

    // prologue: A(0), B(0), B(1) staged; wait all but B(1)'s 4
    stageA(0, 0);
    stageB(0, 0);
    stageB(1, (1 < nK) ? 1 : 0);
    asm volatile("s_waitcnt vmcnt(4)" ::: "memory");
    __builtin_amdgcn_s_barrier();

    for (int tt = 0; tt < nK; ++tt) {
        int tA = (tt + 1 < nK) ? tt + 1 : nK - 1;
        int tB = (tt + 2 < nK) ? tt + 2 : nK - 1;
        int8v af[4], bfr[4];
        // ---- ph1: mh0 ----
        #pragma unroll
        for (int n = 0; n < 4; ++n) bfr[n] = readB(tt, n);
        #pragma unroll
        for (int m = 0; m < 4; ++m) af[m] = readA(tt, m);
        stageA(tt + 1, tA);
        __builtin_amdgcn_s_barrier();
        doQuad(0, af, bfr);
        __builtin_amdgcn_s_barrier();
        // ---- ph2: mh1 ---- (B frags reused)
        #pragma unroll
        for (int m = 0; m < 4; ++m) af[m] = readA(tt, m + 4);
        stageB(tt + 2, tB);
        __builtin_amdgcn_s_barrier();
        doQuad(1, af, bfr);
        asm volatile("s_waitcnt vmcnt(4)" ::: "memory");   // A(t+1),B(t+1) resident; B(t+2) flies
        __builtin_amdgcn_s_barrier();
    }
    asm volatile("s_waitcnt vmcnt(0)" ::: "memory");       // drain tail clamp-stages
    __builtin_amdgcn_s_barrier();

    if (!predMode) {
        // epilogue: h1 = relu(acc/64 + b1) -> fp8.  C row=(lane>>4)*4+j, col=lane&15
        #pragma unroll
        for (int n = 0; n < 4; ++n) {
            int c = nBase + wcn * 64 + n * 16 + lr;
            float bv = bias[c];
            #pragma unroll
            for (int m = 0; m < 8; ++m) {
                int r0 = mBase + wr * 128 + m * 16 + lk * 4;
                #pragma unroll
                for (int j = 0; j < 4; ++j)
                    C[(size_t)(r0 + j) * HID + c] = f2fp8(fmaxf(acc[m][n][j] * WINV + bv, 0.f));
            }
        }
    } else {
        // fused final layer: pred = relu(acc/64+b2) @ W3, LDS-reduced across wcn waves
        float* red = (float*)smem;    // [256 rows][4 wcn][2] = 8KB (LDS drained above)
        float w3v[4][2], bv[4];
        #pragma unroll
        for (int n = 0; n < 4; ++n) {
            int c = nBase + wcn * 64 + n * 16 + lr;
            w3v[n][0] = W3[c * 2 + 0];
            w3v[n][1] = W3[c * 2 + 1];
            bv[n] = bias[c];
        }
        #pragma unroll
        for (int m = 0; m < 8; ++m) {
            #pragma unroll
            for (int j = 0; j < 4; ++j) {
                float p0 = 0.f, p1 = 0.f;
                #pragma unroll
                for (int n = 0; n < 4; ++n) {
                    float v = fmaxf(acc[m][n][j] * WINV + bv[n], 0.f);
                    p0 += v * w3v[n][0];
                    p1 += v * w3v[n][1];
                }
                #pragma unroll
                for (int msk = 1; msk < 16; msk <<= 1) {   // reduce over the 16 lr-lanes
                    p0 += __shfl_xor(p0, msk);
                    p1 += __shfl_xor(p1, msk);
                }
                if (lr == 0) {
                    int rl = wr * 128 + m * 16 + lk * 4 + j;   // 0..255, unique per (wave,lane)
                    red[rl * 8 + wcn * 2 + 0] = p0;
                    red[rl * 8 + wcn * 2 + 1] = p1;
                }
            }
        }
        __builtin_amdgcn_s_barrier();
        {   // 512 threads: one (row, component) each; 4-way sum; ONE atomic each
            int rl = t >> 1, comp = t & 1;
            float v = red[rl * 8 + 0 * 2 + comp] + red[rl * 8 + 1 * 2 + comp]
                    + red[rl * 8 + 2 * 2 + comp] + red[rl * 8 + 3 * 2 + comp];
            atomicAdd(&out[(size_t)(mBase + rl) * 2 + comp], v);   // 2 contenders (nTiles)
        }
    }
}

// ---------- launch ----------
extern "C" void kernel_launch(void* const* d_in, const int* in_sizes, int n_in,
                              void* d_out, int out_size, void* d_ws, size_t ws_size,
                              hipStream_t stream) {
    const float* x  = (const float*)d_in[0];
    const float* W1 = (const float*)d_in[1];
    const float* b1 = (const float*)d_in[2];
    const float* W2 = (const float*)d_in[3];
    const float* b2 = (const float*)d_in[4];
    const float* W3 = (const float*)d_in[5];
    const float* b3 = (const float*)d_in[6];
    const int*  pxs = (const int*)d_in[7];
    const int*  pys = (const int*)d_in[8];
    float* out = (float*)d_out;
    char* ws = (char*)d_ws;

    // ws layout (bytes), fp8: W1t 786,432 | W2t 262,144 | h1 25,690,112 | feats 77,070,336
    unsigned char* W1t   = (unsigned char*)(ws + 0);
    unsigned char* W2t   = (unsigned char*)(ws + 786432);
    unsigned char* h1    = (unsigned char*)(ws + 1048576);
    unsigned char* feats = (unsigned char*)(ws + 26738688);   // end 103,809,024

    hipFuncSetAttribute((const void*)gemm_mx,
                        hipFuncAttributeMaxDynamicSharedMemorySize, 163840);

    transpose_cast_fp8<<<(K1 * HID + 255) / 256, 256, 0, stream>>>(W1, W1t, K1, HID);
    transpose_cast_fp8<<<(HID * HID + 255) / 256, 256, 0, stream>>>(W2, W2t, HID, HID);
    // gather also initializes out: pred rows = b3 (GEMM2 atomics accumulate), deltaxy written
    gather_feats<<<dim3(12, BATCH), 256, 0, stream>>>(x, pxs, pys, b3, feats, out);
    // GEMM1: h1 = relu(feats @ (64*W1t)^T /64 + b1)   grid = 196 mTiles * 2 nTiles = 392
    gemm_mx<<<(MROWS / 256) * 2, 512, 163840, stream>>>(
        feats, W1t, b1, h1, nullptr, nullptr, K1, 0);
    // GEMM2 (+fused GEMM3): out[0:2M) += relu(h1 @ (64*W2t)^T /64 + b2) @ W3
    gemm_mx<<<(MROWS / 256) * 2, 512, 163840, stream>>>(
        h1, W2t, b2, nullptr, W3, out, HID, 1);
}